// Round 5
// baseline (189.969 us; speedup 1.0000x reference)
//
#include <hip/hip_runtime.h>
#include <float.h>

// Batched 1D linear interpolation with clamped extrapolation.
// t: [B,N] sorted fp32, v: [B,N] fp32, r: [B,M] fp32 -> out: [B,M] fp32
constexpr int B = 2048;
constexpr int N = 4096;
constexpr int M = 4096;
constexpr int K = 4080;  // LDS: st (N+8)*4 + sv N*4 + lut K*2 = 16416+16384+8160 = 40960 B
constexpr int T = 512;   // 4 blocks/CU x 8 waves = 32 waves/CU

// Select w[m] for m in [0,5] with 5 cndmasks (no LDS).
__device__ __forceinline__ float sel6(const float* w, int m) {
    const float x0 = (m & 1) ? w[1] : w[0];
    const float x2 = (m & 1) ? w[3] : w[2];
    const float x4 = (m & 1) ? w[5] : w[4];
    const float y0 = (m & 2) ? x2 : x0;
    return (m & 4) ? x4 : y0;
}

__global__ __launch_bounds__(T, 8) void interp_kernel(
    const float* __restrict__ t,
    const float* __restrict__ v,
    const float* __restrict__ r,
    float* __restrict__ out) {
    __shared__ __align__(16) float st[N + 8];       // st[N..N+7] = +inf sentinels
    __shared__ __align__(16) float sv[N];
    __shared__ unsigned short lut[K];               // lut[k] = first j with (int)(t[j]*K) >= k; else N

    const int tid = threadIdx.x;
    const int b = blockIdx.x;
    const float* tb = t + (size_t)b * N;
    const float* vb = v + (size_t)b * N;
    const float4* r4 = (const float4*)(r + (size_t)b * M);
    float4* o4 = (float4*)(out + (size_t)b * M);

    // Queries first: HBM latency hides under staging + lut fill.
    const float4 qa = r4[tid];
    const float4 qb = r4[tid + T];

    // Stage t/v (coalesced float4); sentinels; packed u32 lut init.
    for (int i = tid; i < N / 4; i += T) {
        ((float4*)st)[i] = ((const float4*)tb)[i];
        ((float4*)sv)[i] = ((const float4*)vb)[i];
    }
    if (tid < 8) st[N + tid] = FLT_MAX;
    for (int i = tid; i < K / 2; i += T)
        ((unsigned int*)lut)[i] = ((unsigned)N << 16) | (unsigned)N;
    __syncthreads();

    // Range-fill: element j claims buckets ((int)(t[j-1]*K), (int)(t[j]*K)].
    // Disjoint -> no races; u16 LDS writes are byte-enable safe.
    for (int j = tid; j < N; j += T) {
        const float tj = st[j];
        int khi = (int)(tj * (float)K);
        if (khi > K - 1) khi = K - 1;
        const int klo = (j > 0) ? (int)(st[j - 1] * (float)K) + 1 : 0;
        for (int k = klo; k <= khi; ++k) lut[k] = (unsigned short)j;
    }
    __syncthreads();

    const float tfirst = st[0];
    const float vfirst = sv[0];
    const float tlast = st[N - 1];
    const float vlast = sv[N - 1];

    float o[8];
    const float4 qq[2] = {qa, qb};
    #pragma unroll
    for (int pass = 0; pass < 2; ++pass) {
        float q[4] = {qq[pass].x, qq[pass].y, qq[pass].z, qq[pass].w};
        int ja[4];
        float w[4][6];
        int cnt[4];
        int idx[4];

        // Level 1: lut reads (all 4 issued together).
        // Invariant: every j < lut[k] has t[j] < q, so the window anchored at
        // (lut[k]-1)&~1 contains the t[j]>q transition unless all 6 are <= q.
        #pragma unroll
        for (int j = 0; j < 4; ++j) {
            int k = (int)(q[j] * (float)K);
            k = k < 0 ? 0 : (k > K - 1 ? K - 1 : k);
            int lo = lut[k];
            lo = lo < 1 ? 1 : lo;
            ja[j] = (lo - 1) & ~1;   // 8B-aligned, includes t[idx-1]
        }
        // Level 2: 6-float windows (ds_read2_b64 + ds_read_b64 per query).
        #pragma unroll
        for (int j = 0; j < 4; ++j) {
            const float2* p = (const float2*)(st + ja[j]);
            const float2 w01 = p[0];
            const float2 w23 = p[1];
            const float2 w45 = p[2];
            w[j][0] = w01.x; w[j][1] = w01.y;
            w[j][2] = w23.x; w[j][3] = w23.y;
            w[j][4] = w45.x; w[j][5] = w45.y;
        }
        // Resolve in registers: idx = ja + popcount(w <= q); sortedness makes
        // this the first index with t > q, provided w[5] > q.
        #pragma unroll
        for (int j = 0; j < 4; ++j) {
            int c = 0;
            #pragma unroll
            for (int s = 0; s < 6; ++s) c += (w[j][s] <= q[j]) ? 1 : 0;
            int ix = ja[j] + c;
            if (c == 6) {               // rare (~0.1%/query): walk past window
                int l = ja[j] + 6;
                while (st[l] <= q[j]) ++l;   // inf sentinels bound the walk
                ix = l;
                w[j][4] = st[ix - 1];   // stash pair where the trees select it
                w[j][5] = st[ix];
                c = 5;
            }
            cnt[j] = c;
            idx[j] = ix;
        }
        // Level 3: sv pair fetches (ds_read2_b32), all 4 issued together.
        float v0[4], v1[4];
        #pragma unroll
        for (int j = 0; j < 4; ++j) {
            int ic = idx[j];
            ic = ic < 1 ? 1 : (ic > N - 1 ? N - 1 : ic);
            v0[j] = sv[ic - 1];
            v1[j] = sv[ic];
        }
        // Select t0/t1 from the window (VALU only) + interp math (fast rcp).
        #pragma unroll
        for (int j = 0; j < 4; ++j) {
            const int m1 = cnt[j];
            const int m0 = m1 > 0 ? m1 - 1 : 0;
            const float t1 = sel6(w[j], m1);
            const float t0 = sel6(w[j], m0);
            const float d = t1 - t0;
            const float rden = __builtin_amdgcn_rcpf(d == 0.0f ? 1.0f : d);
            float oo = v0[j] + (q[j] - t0) * rden * (v1[j] - v0[j]);
            oo = (q[j] < tfirst) ? vfirst : oo;
            oo = (q[j] > tlast) ? vlast : oo;
            o[pass * 4 + j] = oo;
        }
    }
    o4[tid] = make_float4(o[0], o[1], o[2], o[3]);
    o4[tid + T] = make_float4(o[4], o[5], o[6], o[7]);
}

extern "C" void kernel_launch(void* const* d_in, const int* in_sizes, int n_in,
                              void* d_out, int out_size, void* d_ws, size_t ws_size,
                              hipStream_t stream) {
    const float* t = (const float*)d_in[0];
    const float* v = (const float*)d_in[1];
    const float* r = (const float*)d_in[2];
    float* out = (float*)d_out;
    interp_kernel<<<B, T, 0, stream>>>(t, v, r, out);
}

// Round 6
// 139.778 us; speedup vs baseline: 1.3591x; 1.3591x over previous
//
#include <hip/hip_runtime.h>
#include <float.h>

// Batched 1D linear interpolation with clamped extrapolation.
// t: [B,N] sorted fp32, v: [B,N] fp32, r: [B,M] fp32 -> out: [B,M] fp32
constexpr int B = 2048;
constexpr int N = 4096;
constexpr int M = 4096;
constexpr int K = 4072;  // LDS: st (N+8)*4 + sv (N+4)*4 + lut K*2 = 16416+16400+8144 = 40960 B
constexpr int T = 512;   // 4 blocks/CU x 8 waves = 32 waves/CU

__global__ __launch_bounds__(T, 8) void interp_kernel(
    const float* __restrict__ t,
    const float* __restrict__ v,
    const float* __restrict__ r,
    float* __restrict__ out) {
    __shared__ __align__(16) float st[N + 8];   // st[N..N+7] = +inf sentinels
    __shared__ __align__(16) float sv[N + 4];   // sv[N..N+1] = 0 (defined idx==N corner)
    __shared__ unsigned short lut[K];           // lut[k] = first j with (int)(t[j]*K) >= k (<= N-1)

    const int tid = threadIdx.x;
    const int b = blockIdx.x;
    const float* tb = t + (size_t)b * N;
    const float* vb = v + (size_t)b * N;
    const float4* r4 = (const float4*)(r + (size_t)b * M);
    float4* o4 = (float4*)(out + (size_t)b * M);

    // Queries first: HBM latency hides under staging + fill.
    const float4 qa = r4[tid];
    const float4 qb = r4[tid + T];

    if (tid < 8) st[N + tid] = FLT_MAX;
    if (tid < 4) sv[N + tid] = 0.0f;

    // Merged stage + lut range-fill (single barrier). The fill uses the staged
    // float4 still in registers; t[j-1] comes from __shfl_up (wave-boundary
    // lanes re-read one L1-hot scalar). Element j claims buckets
    // ((int)(t[j-1]*K), (int)(t[j]*K)]; disjoint -> no races; the j==N-1 owner
    // extends to K-1, so no separate lut-init pass and no lut value exceeds N-1.
    #pragma unroll
    for (int it = 0; it < 2; ++it) {
        const int i = tid + it * T;             // float4 index 0..N/4-1
        const float4 t4 = ((const float4*)tb)[i];
        const float4 v4 = ((const float4*)vb)[i];
        ((float4*)st)[i] = t4;
        ((float4*)sv)[i] = v4;
        float tprev = __shfl_up(t4.w, 1);
        if ((tid & 63) == 0 && i > 0) tprev = tb[4 * i - 1];
        const float pe[4] = {tprev, t4.x, t4.y, t4.z};
        const float ce[4] = {t4.x, t4.y, t4.z, t4.w};
        #pragma unroll
        for (int e = 0; e < 4; ++e) {
            const int j = 4 * i + e;
            int khi = (int)(ce[e] * (float)K);
            khi = khi > K - 1 ? K - 1 : khi;
            if (j == N - 1) khi = K - 1;        // claim the tail buckets
            const int klo = (j == 0) ? 0 : (int)(pe[e] * (float)K) + 1;
            for (int k = klo; k <= khi; ++k) lut[k] = (unsigned short)j;
        }
    }
    __syncthreads();

    const float tfirst = st[0];
    const float vfirst = sv[0];
    const float tlast = st[N - 1];
    const float vlast = sv[N - 1];

    float o[8];
    const float qs[8] = {qa.x, qa.y, qa.z, qa.w, qb.x, qb.y, qb.z, qb.w};
    #pragma unroll
    for (int pass = 0; pass < 2; ++pass) {
        float q[4];
        int bs[4];
        float a0[4], a1[4], a2[4], a3[4];
        float tt0[4], tt1[4];
        int idx[4];
        float v0[4], v1[4];

        // Level 1: lut reads, all 4 issued together.
        // Invariant: bucket(t[lut[k]-1]) < k <= bucket(q) -> t[base] <= q.
        #pragma unroll
        for (int j = 0; j < 4; ++j) {
            q[j] = qs[pass * 4 + j];
            int k = (int)(q[j] * (float)K);
            k = k < 0 ? 0 : (k > K - 1 ? K - 1 : k);
            int lo = lut[k];
            lo = lo < 1 ? 1 : lo;
            bs[j] = lo - 1;
        }
        // Level 2: 4-float windows; adjacent scalar reads -> 2x ds_read2_b32
        // per query, mutually independent (both addresses known after level 1).
        #pragma unroll
        for (int j = 0; j < 4; ++j) {
            a0[j] = st[bs[j] + 0];
            a1[j] = st[bs[j] + 1];
            a2[j] = st[bs[j] + 2];
            a3[j] = st[bs[j] + 3];
        }
        // Resolve in registers: idx = base + #{window <= q} (sorted prefix).
        #pragma unroll
        for (int j = 0; j < 4; ++j) {
            int c = (a0[j] <= q[j] ? 1 : 0) + (a1[j] <= q[j] ? 1 : 0) +
                    (a2[j] <= q[j] ? 1 : 0) + (a3[j] <= q[j] ? 1 : 0);
            c = c < 1 ? 1 : c;          // q < t[base] only when q < t[0]: clamped later
            float t0 = (c >= 2) ? ((c >= 3) ? a2[j] : a1[j]) : a0[j];
            float t1 = (c >= 2) ? ((c >= 3) ? a3[j] : a2[j]) : a1[j];
            int ix = bs[j] + c;
            if (c == 4) {               // rare (~1.4%): transition past window
                float tp = a3[j];
                int l = bs[j] + 4;
                float tc = st[l];
                while (tc <= q[j]) { tp = tc; ++l; tc = st[l]; }  // inf-bounded
                t0 = tp; t1 = tc; ix = l;
            }
            tt0[j] = t0; tt1[j] = t1; idx[j] = ix;
        }
        // Level 3: sv pairs (ds_read2_b32), all 4 issued together.
        #pragma unroll
        for (int j = 0; j < 4; ++j) {
            v0[j] = sv[idx[j] - 1];
            v1[j] = sv[idx[j]];
        }
        // Interp math; idx==N corner: t1=inf -> rcp(inf)=0 -> oo = v[N-1]. ✓
        #pragma unroll
        for (int j = 0; j < 4; ++j) {
            const float d = tt1[j] - tt0[j];
            const float rden = __builtin_amdgcn_rcpf(d == 0.0f ? 1.0f : d);
            float oo = v0[j] + (q[j] - tt0[j]) * rden * (v1[j] - v0[j]);
            oo = (q[j] < tfirst) ? vfirst : oo;
            oo = (q[j] > tlast) ? vlast : oo;
            o[pass * 4 + j] = oo;
        }
    }
    o4[tid] = make_float4(o[0], o[1], o[2], o[3]);
    o4[tid + T] = make_float4(o[4], o[5], o[6], o[7]);
}

extern "C" void kernel_launch(void* const* d_in, const int* in_sizes, int n_in,
                              void* d_out, int out_size, void* d_ws, size_t ws_size,
                              hipStream_t stream) {
    const float* t = (const float*)d_in[0];
    const float* v = (const float*)d_in[1];
    const float* r = (const float*)d_in[2];
    float* out = (float*)d_out;
    interp_kernel<<<B, T, 0, stream>>>(t, v, r, out);
}

// Round 7
// 135.309 us; speedup vs baseline: 1.4040x; 1.0330x over previous
//
#include <hip/hip_runtime.h>
#include <float.h>

// Batched 1D linear interpolation with clamped extrapolation.
// t: [B,N] sorted fp32, v: [B,N] fp32, r: [B,M] fp32 -> out: [B,M] fp32
constexpr int B = 2048;
constexpr int N = 4096;
constexpr int M = 4096;
constexpr int K = 4072;  // LDS: st (N+8)*4 + sv (N+4)*4 + lut K*2 = 16416+16400+8144 = 40960 B
constexpr int T = 512;   // 4 blocks/CU x 8 waves = 32 waves/CU

__global__ __launch_bounds__(T, 8) void interp_kernel(
    const float* __restrict__ t,
    const float* __restrict__ v,
    const float* __restrict__ r,
    float* __restrict__ out) {
    __shared__ __align__(16) float st[N + 8];   // st[N..N+7] = +inf sentinels
    __shared__ __align__(16) float sv[N + 4];   // sv[N..N+3] = 0 (defined idx==N corner)
    __shared__ unsigned short lut[K];           // lut[k] = first j with (int)(t[j]*K) >= k (<= N-1)

    const int tid = threadIdx.x;
    const int b = blockIdx.x;
    const float* tb = t + (size_t)b * N;
    const float* vb = v + (size_t)b * N;
    const float4* r4 = (const float4*)(r + (size_t)b * M);
    float4* o4 = (float4*)(out + (size_t)b * M);

    // ALL global loads upfront (6 float4s in flight, one vmcnt group).
    // R6's regression: round-2 staging loads serialized behind round-1's fill.
    const float4 t4a = ((const float4*)tb)[tid];
    const float4 t4b = ((const float4*)tb)[tid + T];
    const float4 v4a = ((const float4*)vb)[tid];
    const float4 v4b = ((const float4*)vb)[tid + T];
    const float4 qa = r4[tid];
    const float4 qb = r4[tid + T];

    if (tid < 8) st[N + tid] = FLT_MAX;
    if (tid < 4) sv[N + tid] = 0.0f;

    ((float4*)st)[tid]     = t4a;
    ((float4*)st)[tid + T] = t4b;
    ((float4*)sv)[tid]     = v4a;
    ((float4*)sv)[tid + T] = v4b;

    // lut range-fill straight from the staged registers (no LDS reads, single
    // barrier). Element j claims buckets ((int)(t[j-1]*K), (int)(t[j]*K)];
    // disjoint -> no races; j==N-1 extends to K-1 (replaces lut-init pass).
    {
        float tpa = __shfl_up(t4a.w, 1);
        if ((tid & 63) == 0 && tid > 0) tpa = tb[4 * tid - 1];
        float tpb = __shfl_up(t4b.w, 1);
        if ((tid & 63) == 0) tpb = tb[4 * (tid + T) - 1];
        const float pe[8] = {tpa, t4a.x, t4a.y, t4a.z, tpb, t4b.x, t4b.y, t4b.z};
        const float ce[8] = {t4a.x, t4a.y, t4a.z, t4a.w, t4b.x, t4b.y, t4b.z, t4b.w};
        #pragma unroll
        for (int e = 0; e < 8; ++e) {
            const int j = (e < 4 ? 4 * tid : 4 * (tid + T)) + (e & 3);
            int khi = (int)(ce[e] * (float)K);
            khi = khi > K - 1 ? K - 1 : khi;
            if (j == N - 1) khi = K - 1;        // claim the tail buckets
            const int klo = (j == 0) ? 0 : (int)(pe[e] * (float)K) + 1;
            for (int k = klo; k <= khi; ++k) lut[k] = (unsigned short)j;
        }
    }
    __syncthreads();

    const float tfirst = st[0];
    const float vfirst = sv[0];
    const float tlast = st[N - 1];
    const float vlast = sv[N - 1];

    // Query phase: single 8-wide pass for max MLP. Chain depth 3:
    // lut (8 indep) -> window (16 indep ds_read2_b32) -> sv pair (8 indep).
    const float q[8] = {qa.x, qa.y, qa.z, qa.w, qb.x, qb.y, qb.z, qb.w};
    int bs[8];
    float a0[8], a1[8], a2[8], a3[8];
    float tt0[8], tt1[8];
    int idx[8];
    float v0[8], v1[8];
    float o[8];

    // Level 1: lut reads. Invariant: bucket(t[lut[k]-1]) < k <= bucket(q)
    // -> t[base] <= q (except q < t[0], fixed by the c-clamp + final clamp).
    #pragma unroll
    for (int j = 0; j < 8; ++j) {
        int k = (int)(q[j] * (float)K);
        k = k < 0 ? 0 : (k > K - 1 ? K - 1 : k);
        int lo = lut[k];
        lo = lo < 1 ? 1 : lo;
        bs[j] = lo - 1;
    }
    // Level 2: 4-float windows (adjacent scalars -> 2x ds_read2_b32 each).
    #pragma unroll
    for (int j = 0; j < 8; ++j) {
        a0[j] = st[bs[j] + 0];
        a1[j] = st[bs[j] + 1];
        a2[j] = st[bs[j] + 2];
        a3[j] = st[bs[j] + 3];
    }
    // Resolve in registers: idx = base + #{window <= q} (sorted prefix count).
    #pragma unroll
    for (int j = 0; j < 8; ++j) {
        int c = (a0[j] <= q[j] ? 1 : 0) + (a1[j] <= q[j] ? 1 : 0) +
                (a2[j] <= q[j] ? 1 : 0) + (a3[j] <= q[j] ? 1 : 0);
        c = c < 1 ? 1 : c;
        float t0 = (c >= 2) ? ((c >= 3) ? a2[j] : a1[j]) : a0[j];
        float t1 = (c >= 2) ? ((c >= 3) ? a3[j] : a2[j]) : a1[j];
        int ix = bs[j] + c;
        if (c == 4) {               // rare (~1.4%/query): walk past window
            float tp = a3[j];
            int l = bs[j] + 4;
            float tc = st[l];
            while (tc <= q[j]) { tp = tc; ++l; tc = st[l]; }  // inf-bounded
            t0 = tp; t1 = tc; ix = l;
        }
        tt0[j] = t0; tt1[j] = t1; idx[j] = ix;
    }
    // Level 3: sv pairs (ds_read2_b32), all 8 issued together.
    #pragma unroll
    for (int j = 0; j < 8; ++j) {
        v0[j] = sv[idx[j] - 1];
        v1[j] = sv[idx[j]];
    }
    // Interp math; idx==N corner: t1=inf -> rcp -> 0 -> oo=v[N-1], then clamp.
    #pragma unroll
    for (int j = 0; j < 8; ++j) {
        const float d = tt1[j] - tt0[j];
        const float rden = __builtin_amdgcn_rcpf(d == 0.0f ? 1.0f : d);
        float oo = v0[j] + (q[j] - tt0[j]) * rden * (v1[j] - v0[j]);
        oo = (q[j] < tfirst) ? vfirst : oo;
        oo = (q[j] > tlast) ? vlast : oo;
        o[j] = oo;
    }
    o4[tid]     = make_float4(o[0], o[1], o[2], o[3]);
    o4[tid + T] = make_float4(o[4], o[5], o[6], o[7]);
}

extern "C" void kernel_launch(void* const* d_in, const int* in_sizes, int n_in,
                              void* d_out, int out_size, void* d_ws, size_t ws_size,
                              hipStream_t stream) {
    const float* t = (const float*)d_in[0];
    const float* v = (const float*)d_in[1];
    const float* r = (const float*)d_in[2];
    float* out = (float*)d_out;
    interp_kernel<<<B, T, 0, stream>>>(t, v, r, out);
}